// Round 10
// baseline (53.329 us; speedup 1.0000x reference)
//
#include <hip/hip_runtime.h>

// DCN cross net, algebraically unrolled. Round 9: copy-shaped pipelined wave.
//  - 1024 blocks x 4 waves (4 blocks/CU); each wave owns 4 CONSECUTIVE pairs
//    (8 rows = 32 KB sequential read + 32 KB sequential write).
//  - w + Bsum staged in LDS once per block; steady-state VMEM = x loads +
//    out stores only (copy-shaped).
//  - fully-unrolled 2-deep ping-pong: load pair i+1 while compute/store pair i
//    -> every wave always has 8 KB of loads in flight (fixes round-4's duty
//    cycle without round-5's occupancy loss / locality loss).

#define DCN_D 1024
#define DCN_F4 (DCN_D / 4)   // 256 float4 per row
#define PAIRS_PER_WAVE 4

// ws layout: ws[0..1023] = Bsum; ws[1024..1029] = {c01,c02,c12,c03,c13,c23}

__global__ __launch_bounds__(256) void dcn_pre_kernel(
    const float* __restrict__ w,   // [4, D]
    const float* __restrict__ b,   // [4, D]
    float* __restrict__ ws)
{
    const int t = threadIdx.x;
    for (int d = t; d < DCN_D; d += 256)
        ws[d] = b[d] + b[DCN_D + d] + b[2 * DCN_D + d] + b[3 * DCN_D + d];
    float p[6] = {0, 0, 0, 0, 0, 0};
    for (int d = t; d < DCN_D; d += 256) {
        const float b0 = b[d], b1 = b[DCN_D + d], b2 = b[2 * DCN_D + d];
        const float w1 = w[DCN_D + d], w2 = w[2 * DCN_D + d], w3 = w[3 * DCN_D + d];
        p[0] = fmaf(b0, w1, p[0]);
        p[1] = fmaf(b0, w2, p[1]);
        p[2] = fmaf(b1, w2, p[2]);
        p[3] = fmaf(b0, w3, p[3]);
        p[4] = fmaf(b1, w3, p[4]);
        p[5] = fmaf(b2, w3, p[5]);
    }
    __shared__ float red[6][4];
    const int wave = t >> 6, lane = t & 63;
    #pragma unroll
    for (int k = 0; k < 6; ++k) {
        float v = p[k];
        #pragma unroll
        for (int off = 32; off > 0; off >>= 1) v += __shfl_down(v, off, 64);
        if (lane == 0) red[k][wave] = v;
    }
    __syncthreads();
    if (t < 6) ws[DCN_D + t] = red[t][0] + red[t][1] + red[t][2] + red[t][3];
}

__device__ __forceinline__ float dot4acc(const float4 a, const float4 b, float acc) {
    return fmaf(a.x, b.x, fmaf(a.y, b.y, fmaf(a.z, b.z, fmaf(a.w, b.w, acc))));
}

__global__ __launch_bounds__(256) void dcn_main_kernel(
    const float* __restrict__ x,
    const float* __restrict__ w,
    const float* __restrict__ ws,
    float* __restrict__ out,
    int B)
{
    __shared__ float4 w_lds[4 * DCN_F4];   // 16 KB
    __shared__ float4 b_lds[DCN_F4];       //  4 KB

    const int t      = (int)threadIdx.x;
    const int lane   = t & 63;
    const int wib    = t >> 6;
    const int wid    = (int)blockIdx.x * 4 + wib;
    const int npairs = B >> 1;
    const int pair0  = wid * PAIRS_PER_WAVE;

    float4 xA[2][4], xB[2][4];

#define LOADP(buf, pr) do {                                                      \
    if ((pr) < npairs) {                                                         \
        const float4* __restrict__ _x0 =                                         \
            reinterpret_cast<const float4*>(x + (size_t)(2 * (pr)) * DCN_D);     \
        const float4* __restrict__ _x1 =                                         \
            reinterpret_cast<const float4*>(x + (size_t)(2 * (pr) + 1) * DCN_D); \
        _Pragma("unroll")                                                        \
        for (int j = 0; j < 4; ++j) buf[0][j] = _x0[lane + 64 * j];              \
        _Pragma("unroll")                                                        \
        for (int j = 0; j < 4; ++j) buf[1][j] = _x1[lane + 64 * j];              \
    }                                                                            \
} while (0)

#define COMPP(buf, pr) do {                                                      \
    if ((pr) < npairs) {                                                         \
        float p0[4] = {0, 0, 0, 0}, p1[4] = {0, 0, 0, 0};                        \
        _Pragma("unroll")                                                        \
        for (int j = 0; j < 4; ++j) {                                            \
            const int idx = lane + 64 * j;                                       \
            _Pragma("unroll")                                                    \
            for (int l = 0; l < 4; ++l) {                                        \
                const float4 wv = w_lds[l * DCN_F4 + idx];                       \
                p0[l] = dot4acc(buf[0][j], wv, p0[l]);                           \
                p1[l] = dot4acc(buf[1][j], wv, p1[l]);                           \
            }                                                                    \
        }                                                                        \
        _Pragma("unroll")                                                        \
        for (int off = 1; off < 64; off <<= 1) {                                 \
            _Pragma("unroll")                                                    \
            for (int l = 0; l < 4; ++l) {                                        \
                p0[l] += __shfl_xor(p0[l], off, 64);                             \
                p1[l] += __shfl_xor(p1[l], off, 64);                             \
            }                                                                    \
        }                                                                        \
        const float t1a = 1.f + p0[0];                                           \
        const float s1a = fmaf(p0[1], t1a, c01);                                 \
        const float t2a = t1a + s1a;                                             \
        const float s2a = fmaf(p0[2], t2a, c2sum);                               \
        const float t3a = t2a + s2a;                                             \
        const float s3a = fmaf(p0[3], t3a, c3sum);                               \
        const float S0  = t3a + s3a;                                             \
        const float t1b = 1.f + p1[0];                                           \
        const float s1b = fmaf(p1[1], t1b, c01);                                 \
        const float t2b = t1b + s1b;                                             \
        const float s2b = fmaf(p1[2], t2b, c2sum);                               \
        const float t3b = t2b + s2b;                                             \
        const float s3b = fmaf(p1[3], t3b, c3sum);                               \
        const float S1  = t3b + s3b;                                             \
        float4* __restrict__ _o0 =                                               \
            reinterpret_cast<float4*>(out + (size_t)(2 * (pr)) * DCN_D);         \
        float4* __restrict__ _o1 =                                               \
            reinterpret_cast<float4*>(out + (size_t)(2 * (pr) + 1) * DCN_D);     \
        _Pragma("unroll")                                                        \
        for (int j = 0; j < 4; ++j) {                                            \
            const int idx = lane + 64 * j;                                       \
            const float4 bb = b_lds[idx];                                        \
            float4 a;                                                            \
            a.x = fmaf(buf[0][j].x, S0, bb.x);                                   \
            a.y = fmaf(buf[0][j].y, S0, bb.y);                                   \
            a.z = fmaf(buf[0][j].z, S0, bb.z);                                   \
            a.w = fmaf(buf[0][j].w, S0, bb.w);                                   \
            _o0[idx] = a;                                                        \
            float4 c;                                                            \
            c.x = fmaf(buf[1][j].x, S1, bb.x);                                   \
            c.y = fmaf(buf[1][j].y, S1, bb.y);                                   \
            c.z = fmaf(buf[1][j].z, S1, bb.z);                                   \
            c.w = fmaf(buf[1][j].w, S1, bb.w);                                   \
            _o1[idx] = c;                                                        \
        }                                                                        \
    }                                                                            \
} while (0)

    // pair 0 x-loads first: ride out the staging barrier
    LOADP(xA, pair0);

    // stage w + Bsum into LDS (once per block)
    const float4* __restrict__ w4  = reinterpret_cast<const float4*>(w);
    const float4* __restrict__ bs4 = reinterpret_cast<const float4*>(ws);
    #pragma unroll
    for (int i = 0; i < 4; ++i) w_lds[t + 256 * i] = w4[t + 256 * i];
    b_lds[t] = bs4[t];
    const float c01   = ws[DCN_D + 0];
    const float c2sum = ws[DCN_D + 1] + ws[DCN_D + 2];
    const float c3sum = ws[DCN_D + 3] + ws[DCN_D + 4] + ws[DCN_D + 5];
    __syncthreads();

    // 2-deep ping-pong over 4 consecutive pairs
    LOADP(xB, pair0 + 1);
    COMPP(xA, pair0);
    LOADP(xA, pair0 + 2);
    COMPP(xB, pair0 + 1);
    LOADP(xB, pair0 + 3);
    COMPP(xA, pair0 + 2);
    COMPP(xB, pair0 + 3);

#undef LOADP
#undef COMPP
}

extern "C" void kernel_launch(void* const* d_in, const int* in_sizes, int n_in,
                              void* d_out, int out_size, void* d_ws, size_t ws_size,
                              hipStream_t stream) {
    const float* x = (const float*)d_in[0];
    const float* w = (const float*)d_in[1];
    const float* b = (const float*)d_in[2];
    float* out = (float*)d_out;
    float* ws = (float*)d_ws;
    const int B = in_sizes[0] / DCN_D;

    dcn_pre_kernel<<<1, 256, 0, stream>>>(w, b, ws);
    // 4 waves/block, 4 pairs/wave -> 32 rows per block
    const int rows_per_block = 2 * PAIRS_PER_WAVE * 4;
    dcn_main_kernel<<<(B + rows_per_block - 1) / rows_per_block, 256, 0, stream>>>(
        x, w, ws, out, B);
}